// Round 4
// baseline (877.468 us; speedup 1.0000x reference)
//
#include <hip/hip_runtime.h>
#include <hip/hip_bf16.h>

// ---------------- constants (match reference) ----------------
#define DIM_IN 1000
#define HEADS 8
#define HID 8
#define DIM_OUT 32
#define NEG_SLOPE 0.2f

// ---------------- GEMM1 split-K: out[N,128] = x[N,1000] @ [W1 | W2a] ----------------
// grid.y = 0: k 0..511   -> hp1, p2
// grid.y = 1: k 512..999 -> tmpA, tmpB (merged afterwards)
__global__ __launch_bounds__(256) void gemm_x_fused(
    const float* __restrict__ x, const float* __restrict__ W1,
    const float* __restrict__ W2, float* __restrict__ hp1,
    float* __restrict__ p2, float* __restrict__ tmpA,
    float* __restrict__ tmpB, int N)
{
    __shared__ float xs[128][33];                 // [row][k], +1 pad banks
    __shared__ __align__(16) float ws[32][128];   // [k][col]
    const int tid = threadIdx.x;
    const int rowbase = blockIdx.x * 128;
    const int kbase = blockIdx.y * 512;
    float* outA = blockIdx.y ? tmpA : hp1;
    float* outB = blockIdx.y ? tmpB : p2;

    const int row0 = (tid >> 4) * 8;   // 8 rows per thread
    const int cA = (tid & 15) * 4;     // cols cA..cA+3

    float accA[8][4] = {};
    float accB[8][4] = {};
    float4 rx[4], rw[4];

    auto load_tile = [&](int k0) {
#pragma unroll
        for (int i = 0; i < 4; i++) {
            int f4 = tid + i * 256;
            int r = f4 >> 3;             // 0..127
            int kq = (f4 & 7) * 4;       // 0,4,...,28
            int gr = rowbase + r, gk = k0 + kq;
            float4 v = {0.f, 0.f, 0.f, 0.f};
            if (gr < N && gk + 3 < DIM_IN)
                v = *(const float4*)&x[(size_t)gr * DIM_IN + gk];
            rx[i] = v;
        }
#pragma unroll
        for (int i = 0; i < 4; i++) {
            int f4 = tid + i * 256;
            int kk = f4 >> 5;            // 0..31
            int cq = (f4 & 31) * 4;      // 0..124
            int gk = k0 + kk;
            float4 v = {0.f, 0.f, 0.f, 0.f};
            if (gk < DIM_IN)
                v = (cq < 64) ? *(const float4*)&W1[(size_t)gk * 64 + cq]
                              : *(const float4*)&W2[(size_t)gk * 64 + (cq - 64)];
            rw[i] = v;
        }
    };

    auto store_tile = [&]() {
#pragma unroll
        for (int i = 0; i < 4; i++) {
            int f4 = tid + i * 256;
            int r = f4 >> 3, kq = (f4 & 7) * 4;
            xs[r][kq + 0] = rx[i].x;
            xs[r][kq + 1] = rx[i].y;
            xs[r][kq + 2] = rx[i].z;
            xs[r][kq + 3] = rx[i].w;
        }
#pragma unroll
        for (int i = 0; i < 4; i++) {
            int f4 = tid + i * 256;
            int kk = f4 >> 5, cq = (f4 & 31) * 4;
            *(float4*)&ws[kk][cq] = rw[i];
        }
    };

    load_tile(kbase);
    const int NT = 16;                   // 16 tiles of 32 per k-half
    for (int t = 0; t < NT; t++) {
        __syncthreads();
        store_tile();
        __syncthreads();
        if (t + 1 < NT) load_tile(kbase + (t + 1) * 32);
#pragma unroll
        for (int kk = 0; kk < 32; kk++) {
            float4 b0 = *(const float4*)&ws[kk][cA];
            float4 b1 = *(const float4*)&ws[kk][64 + cA];
#pragma unroll
            for (int r = 0; r < 8; r++) {
                float a = xs[row0 + r][kk];
                accA[r][0] += a * b0.x; accA[r][1] += a * b0.y;
                accA[r][2] += a * b0.z; accA[r][3] += a * b0.w;
                accB[r][0] += a * b1.x; accB[r][1] += a * b1.y;
                accB[r][2] += a * b1.z; accB[r][3] += a * b1.w;
            }
        }
    }

#pragma unroll
    for (int r = 0; r < 8; r++) {
        int gr = rowbase + row0 + r;
        if (gr >= N) continue;
        *(float4*)&outA[(size_t)gr * 64 + cA] = *(float4*)accA[r];
        *(float4*)&outB[(size_t)gr * 64 + cA] = *(float4*)accB[r];
    }
}

// ---------------- merge split-K halves ----------------
__global__ __launch_bounds__(256) void merge_add(
    float* __restrict__ hp1, float* __restrict__ p2,
    const float* __restrict__ tA, const float* __restrict__ tB, int n4)
{
    int i = blockIdx.x * blockDim.x + threadIdx.x;
    if (i >= n4) return;
    float4 a = ((const float4*)hp1)[i];
    float4 b = ((const float4*)tA)[i];
    a.x += b.x; a.y += b.y; a.z += b.z; a.w += b.w;
    ((float4*)hp1)[i] = a;
    float4 c = ((const float4*)p2)[i];
    float4 d = ((const float4*)tB)[i];
    c.x += d.x; c.y += d.y; c.z += d.z; c.w += d.w;
    ((float4*)p2)[i] = c;
}

// ---------------- small GEMM, K=64, NC=64, out += A@W ----------------
__global__ __launch_bounds__(256) void gemm_k64_n64_acc(
    const float* __restrict__ A, const float* __restrict__ W,
    float* __restrict__ out, int N)
{
    __shared__ float as_[16][65];
    const int tid = threadIdx.x;
    const int rb = blockIdx.x * 16;
#pragma unroll
    for (int i = 0; i < 4; i++) {
        int idx = tid + i * 256;
        int r = idx >> 6, c = idx & 63;
        int gr = rb + r;
        as_[r][c] = (gr < N) ? A[(size_t)gr * 64 + c] : 0.f;
    }
    __syncthreads();
    const int row = tid >> 4;
    const int col = (tid & 15) * 4;
    float4 acc = {0, 0, 0, 0};
#pragma unroll 8
    for (int k = 0; k < 64; k++) {
        float a = as_[row][k];
        float4 w = *(const float4*)&W[k * 64 + col];
        acc.x += a * w.x; acc.y += a * w.y; acc.z += a * w.z; acc.w += a * w.w;
    }
    int gr = rb + row;
    if (gr < N) {
        float* o = &out[(size_t)gr * 64 + col];
        o[0] += acc.x; o[1] += acc.y; o[2] += acc.z; o[3] += acc.w;
    }
}

// ---------------- attention dots (per-head h layout [N,H,C]) ----------------
template <int C>
__global__ __launch_bounds__(256) void attn_dots(
    const float* __restrict__ h, const float* __restrict__ a_s,
    const float* __restrict__ a_d, float* __restrict__ als,
    float* __restrict__ ald, int NH)
{
    int i = blockIdx.x * blockDim.x + threadIdx.x;  // node*8 + head
    if (i >= NH) return;
    int head = i & 7;
    const float* hp = h + (size_t)i * C;
    float s = 0.f, d = 0.f;
#pragma unroll
    for (int c = 0; c < C; c++) {
        float v = hp[c];
        s += v * a_s[head * C + c];
        d += v * a_d[head * C + c];
    }
    als[i] = s; ald[i] = d;
}

// ---------------- layer-3 attention dots from h2 via wtilde ----------------
__global__ __launch_bounds__(512) void make_wtilde(
    const float* __restrict__ W3, const float* __restrict__ as3,
    const float* __restrict__ ad3, float* __restrict__ wts,
    float* __restrict__ wtd)
{
    int t = threadIdx.x;          // 512 = 8 heads x 64 k
    int h = t >> 6, k = t & 63;
    float s = 0.f, d = 0.f;
#pragma unroll
    for (int c = 0; c < 32; c++) {
        float w = W3[(size_t)k * 256 + h * 32 + c];
        s += w * as3[h * 32 + c];
        d += w * ad3[h * 32 + c];
    }
    wts[h * 64 + k] = s;
    wtd[h * 64 + k] = d;
}

__global__ __launch_bounds__(256) void attn_dots_w(
    const float* __restrict__ h2, const float* __restrict__ wts,
    const float* __restrict__ wtd, float* __restrict__ als,
    float* __restrict__ ald, int NH)
{
    int i = blockIdx.x * blockDim.x + threadIdx.x;  // node*8 + head
    if (i >= NH) return;
    int head = i & 7, node = i >> 3;
    const float* hp = h2 + (size_t)node * 64;
    float s = 0.f, d = 0.f;
#pragma unroll
    for (int c = 0; c < 64; c++) {
        float v = hp[c];
        s += v * wts[head * 64 + c];
        d += v * wtd[head * 64 + c];
    }
    als[i] = s; ald[i] = d;
}

// ---------------- CSR build ----------------
__global__ __launch_bounds__(256) void csr_hist(
    const int* __restrict__ ei, int E, int Etot, int* __restrict__ deg)
{
    int e = blockIdx.x * blockDim.x + threadIdx.x;
    if (e >= Etot) return;
    int d = (e < E) ? ei[E + e] : e - E;
    atomicAdd(&deg[d], 1);
}

__global__ __launch_bounds__(1024) void csr_scan(
    const int* __restrict__ deg, int* __restrict__ rowptr,
    int* __restrict__ cursor, int N)
{
    __shared__ int partial[1024];
    const int t = threadIdx.x;
    const int chunk = (N + 1023) >> 10;
    const int lo = t * chunk;
    const int hi = min(N, lo + chunk);
    int s = 0;
    for (int i = lo; i < hi; i++) s += deg[i];
    partial[t] = s;
    __syncthreads();
    for (int off = 1; off < 1024; off <<= 1) {
        int v = (t >= off) ? partial[t - off] : 0;
        __syncthreads();
        partial[t] += v;
        __syncthreads();
    }
    int run = (t == 0) ? 0 : partial[t - 1];
    for (int i = lo; i < hi; i++) {
        rowptr[i] = run;
        cursor[i] = run;
        run += deg[i];
    }
    if (t == 1023) rowptr[N] = partial[1023];
}

__global__ __launch_bounds__(256) void csr_fill(
    const int* __restrict__ ei, int E, int Etot,
    int* __restrict__ cursor, int* __restrict__ esrc)
{
    int e = blockIdx.x * blockDim.x + threadIdx.x;
    if (e >= Etot) return;
    int s, d;
    if (e < E) { s = ei[e]; d = ei[E + e]; } else { s = d = e - E; }
    int pos = atomicAdd(&cursor[d], 1);
    esrc[pos] = s;
}

// ---------------- fused gather layer (C=64): online softmax + bias + ELU ----------------
__global__ __launch_bounds__(256) void gat_gather64(
    const int* __restrict__ rowptr, const int* __restrict__ esrc,
    const float* __restrict__ als, const float* __restrict__ ald,
    const float* __restrict__ h, const float* __restrict__ bias,
    float* __restrict__ out, int N)
{
    int node = blockIdx.x * 4 + (threadIdx.x >> 6);
    if (node >= N) return;
    int lane = threadIdx.x & 63;
    int head = lane >> 3;
    int start = rowptr[node], end = rowptr[node + 1];
    float aldv = ald[(size_t)node * 8 + head];
    float m = -1e30f, den = 0.f, acc = 0.f;
    for (int i = start; i < end; i++) {
        int s = esrc[i];
        float e = als[(size_t)s * 8 + head] + aldv;
        e = (e > 0.f) ? e : NEG_SLOPE * e;
        float hv = h[(size_t)s * 64 + lane];
        float nm = fmaxf(m, e);
        float sc = __expf(m - nm);
        float ee = __expf(e - nm);
        acc = acc * sc + ee * hv;
        den = den * sc + ee;
        m = nm;
    }
    float v = acc / (den + 1e-16f) + bias[lane];
    out[(size_t)node * 64 + lane] = (v > 0.f) ? v : (__expf(v) - 1.f);
}

// ---------------- layer 3 fully fused: gather h2 (per-head), tiny GEMM with W3,
// head-mean, bias, log_softmax. One wave per node. ----------------
// lane = h*8 + c8: gathers channels c8*8..c8*8+7 of h2 weighted by head-h alpha.
__global__ __launch_bounds__(256) void gat_l3_final(
    const int* __restrict__ rowptr, const int* __restrict__ esrc,
    const float* __restrict__ als, const float* __restrict__ ald,
    const float* __restrict__ h2, const float* __restrict__ W3,
    const float* __restrict__ b3, float* __restrict__ out, int N)
{
    int node = blockIdx.x * 4 + (threadIdx.x >> 6);
    if (node >= N) return;
    int lane = threadIdx.x & 63;
    int h = lane >> 3, c8 = lane & 7;
    int start = rowptr[node], end = rowptr[node + 1];
    float aldv = ald[(size_t)node * 8 + h];
    float m = -1e30f, den = 0.f;
    float acc[8] = {};
    for (int i = start; i < end; i++) {
        int s = esrc[i];
        float e = als[(size_t)s * 8 + h] + aldv;
        e = (e > 0.f) ? e : NEG_SLOPE * e;
        float4 hv0 = *(const float4*)&h2[(size_t)s * 64 + c8 * 8];
        float4 hv1 = *(const float4*)&h2[(size_t)s * 64 + c8 * 8 + 4];
        float nm = fmaxf(m, e);
        float sc = __expf(m - nm);
        float ee = __expf(e - nm);
        acc[0] = acc[0] * sc + ee * hv0.x;
        acc[1] = acc[1] * sc + ee * hv0.y;
        acc[2] = acc[2] * sc + ee * hv0.z;
        acc[3] = acc[3] * sc + ee * hv0.w;
        acc[4] = acc[4] * sc + ee * hv1.x;
        acc[5] = acc[5] * sc + ee * hv1.y;
        acc[6] = acc[6] * sc + ee * hv1.z;
        acc[7] = acc[7] * sc + ee * hv1.w;
        den = den * sc + ee;
        m = nm;
    }
    float inv = 1.f / (den + 1e-16f);
#pragma unroll
    for (int j = 0; j < 8; j++) acc[j] *= inv;

    // tiny GEMM: out[h, q*4..q*4+3] = sum_k agg[h][k] * W3[k][h*32+q*4..]
    // lane (h, q=c8); k = r*8+j lives in lane h*8+r, register acc[j]
    float4 o4 = {0.f, 0.f, 0.f, 0.f};
#pragma unroll
    for (int r = 0; r < 8; r++) {
#pragma unroll
        for (int j = 0; j < 8; j++) {
            float a = __shfl(acc[j], h * 8 + r, 64);
            int k = r * 8 + j;
            float4 w = *(const float4*)&W3[(size_t)k * 256 + h * 32 + c8 * 4];
            o4.x += a * w.x; o4.y += a * w.y; o4.z += a * w.z; o4.w += a * w.w;
        }
    }
    // head-mean: same class quad lives at lanes c8, 8+c8, ..., 56+c8
#pragma unroll
    for (int o = 8; o < 64; o <<= 1) {
        o4.x += __shfl_xor(o4.x, o, 64);
        o4.y += __shfl_xor(o4.y, o, 64);
        o4.z += __shfl_xor(o4.z, o, 64);
        o4.w += __shfl_xor(o4.w, o, 64);
    }
    int cq = c8 * 4;
    o4.x = o4.x * 0.125f + b3[cq + 0];
    o4.y = o4.y * 0.125f + b3[cq + 1];
    o4.z = o4.z * 0.125f + b3[cq + 2];
    o4.w = o4.w * 0.125f + b3[cq + 3];
    // log-softmax over 32 classes (lanes 0..7 hold all, replicated per 8-group)
    float mx = fmaxf(fmaxf(o4.x, o4.y), fmaxf(o4.z, o4.w));
#pragma unroll
    for (int o = 1; o < 8; o <<= 1) mx = fmaxf(mx, __shfl_xor(mx, o, 64));
    float ex = __expf(o4.x - mx) + __expf(o4.y - mx) + __expf(o4.z - mx) + __expf(o4.w - mx);
#pragma unroll
    for (int o = 1; o < 8; o <<= 1) ex += __shfl_xor(ex, o, 64);
    float lse = mx + __logf(ex);
    if (lane < 8) {
        float4 r4 = {o4.x - lse, o4.y - lse, o4.z - lse, o4.w - lse};
        *(float4*)&out[(size_t)node * 32 + cq] = r4;
    }
}

// ---------------- host launch ----------------
extern "C" void kernel_launch(void* const* d_in, const int* in_sizes, int n_in,
                              void* d_out, int out_size, void* d_ws, size_t ws_size,
                              hipStream_t stream)
{
    const float* x   = (const float*)d_in[0];
    const int*   ei  = (const int*)  d_in[1];
    const float* W1  = (const float*)d_in[2];
    const float* as1 = (const float*)d_in[3];
    const float* ad1 = (const float*)d_in[4];
    const float* b1  = (const float*)d_in[5];
    const float* W2  = (const float*)d_in[6];
    const float* as2 = (const float*)d_in[7];
    const float* ad2 = (const float*)d_in[8];
    const float* b2  = (const float*)d_in[9];
    const float* W3  = (const float*)d_in[10];
    const float* as3 = (const float*)d_in[11];
    const float* ad3 = (const float*)d_in[12];
    const float* b3  = (const float*)d_in[13];
    float* out = (float*)d_out;

    const int N = in_sizes[0] / DIM_IN;
    const int E = in_sizes[1] / 2;
    const int Etot = E + N;

    float* ws = (float*)d_ws;
    size_t o = 0;
    float* hp1 = ws + o; o += (size_t)N * 64;    // x@W1 (k-half 0), then merged
    float* p2  = ws + o; o += (size_t)N * 64;    // x@W2a, then h2pre
    float* h1  = ws + o; o += (size_t)N * 64;
    float* h2  = ws + o; o += (size_t)N * 64;
    float* tA  = ws + o; o += (size_t)N * 64;    // k-half 1 partials
    float* tB  = ws + o; o += (size_t)N * 64;
    float* als = ws + o; o += (size_t)N * 8;
    float* ald = ws + o; o += (size_t)N * 8;
    float* wts = ws + o; o += 512;
    float* wtd = ws + o; o += 512;
    int* deg    = (int*)(ws + o); o += N;
    int* rowptr = (int*)(ws + o); o += N + 1;
    int* cursor = (int*)(ws + o); o += N;
    int* esrc   = (int*)(ws + o); o += Etot;
    if (o * 4 > ws_size) return;  // workspace too small -> visible failure

    const int TB = 256;

    // fused split-K GEMM over x
    dim3 g1((N + 127) / 128, 2);
    gemm_x_fused<<<g1, TB, 0, stream>>>(x, W1, W2, hp1, p2, tA, tB, N);
    merge_add<<<(N * 16 + TB - 1) / TB, TB, 0, stream>>>(hp1, p2, tA, tB, N * 16);

    // CSR build (graph shared by all 3 layers)
    hipMemsetAsync(deg, 0, (size_t)N * 4, stream);
    csr_hist<<<(Etot + TB - 1) / TB, TB, 0, stream>>>(ei, E, Etot, deg);
    csr_scan<<<1, 1024, 0, stream>>>(deg, rowptr, cursor, N);
    csr_fill<<<(Etot + TB - 1) / TB, TB, 0, stream>>>(ei, E, Etot, cursor, esrc);

    // ---- layer 1 ----
    attn_dots<8><<<(N * 8 + TB - 1) / TB, TB, 0, stream>>>(hp1, as1, ad1, als, ald, N * 8);
    gat_gather64<<<(N + 3) / 4, TB, 0, stream>>>(rowptr, esrc, als, ald, hp1, b1, h1, N);

    // p2 += h1 @ W2[1000:1064]  -> h2pre
    gemm_k64_n64_acc<<<(N + 15) / 16, TB, 0, stream>>>(h1, W2 + (size_t)DIM_IN * 64, p2, N);

    // ---- layer 2 ----
    attn_dots<8><<<(N * 8 + TB - 1) / TB, TB, 0, stream>>>(p2, as2, ad2, als, ald, N * 8);
    gat_gather64<<<(N + 3) / 4, TB, 0, stream>>>(rowptr, esrc, als, ald, p2, b2, h2, N);

    // ---- layer 3 (restructured: aggregate h2, then tiny per-head GEMM) ----
    make_wtilde<<<1, 512, 0, stream>>>(W3, as3, ad3, wts, wtd);
    attn_dots_w<<<(N * 8 + TB - 1) / TB, TB, 0, stream>>>(h2, wts, wtd, als, ald, N * 8);
    gat_l3_final<<<(N + 3) / 4, TB, 0, stream>>>(rowptr, esrc, als, ald, h2, W3, b3, out, N);
}

// Round 5
// 666.198 us; speedup vs baseline: 1.3171x; 1.3171x over previous
//
#include <hip/hip_runtime.h>
#include <hip/hip_bf16.h>

// ---------------- constants (match reference) ----------------
#define DIM_IN 1000
#define HEADS 8
#define HID 8
#define DIM_OUT 32
#define NEG_SLOPE 0.2f

typedef __attribute__((ext_vector_type(4))) float f32x4;
typedef __attribute__((ext_vector_type(8))) short s16x8;

__device__ __forceinline__ unsigned bf16rne(float f) {
    unsigned u = __float_as_uint(f);
    return (u + 0x7FFFu + ((u >> 16) & 1u)) >> 16;
}
__device__ __forceinline__ unsigned pack2(float lo, float hi) {
    return bf16rne(lo) | (bf16rne(hi) << 16);
}

// ---------------- W pre-pack: fragment-ordered bf16 [32 kt][8 ctg][64 lane][8] ----
// element (kt,ctg,lane,j) = Wall[kt*32 + (lane>>4)*8 + j][ctg*16 + (lane&15)]
// Wall col c: c<64 -> W1[k][c], else W2[k][c-64]; k>=1000 -> 0.
__global__ __launch_bounds__(256) void pack_w(
    const float* __restrict__ W1, const float* __restrict__ W2,
    ushort* __restrict__ wpack)
{
    int t = blockIdx.x * 256 + threadIdx.x;   // 0..16383
    if (t >= 32 * 8 * 64) return;
    int lane = t & 63;
    int ctg = (t >> 6) & 7;
    int kt = t >> 9;
    int c = ctg * 16 + (lane & 15);
    int kbase = kt * 32 + (lane >> 4) * 8;
    ushort v[8] __attribute__((aligned(16)));
#pragma unroll
    for (int j = 0; j < 8; j++) {
        int k = kbase + j;
        float w = 0.f;
        if (k < DIM_IN) w = (c < 64) ? W1[(size_t)k * 64 + c] : W2[(size_t)k * 64 + (c - 64)];
        v[j] = (ushort)bf16rne(w);
    }
    *(uint4*)&wpack[(size_t)t * 8] = *(const uint4*)v;
}

// ---------------- GEMM1 (MFMA bf16): [N,128] = x[N,1000] @ [W1 | W2a] ----------------
// 64-row tile, 4 waves; wave wc computes 64 rows x cols [wc*32, wc*32+32).
// A staged f32->bf16 into fragment-ordered LDS (double-buffered);
// B frags read directly from wpack (global, L2-resident).
__global__ __launch_bounds__(256) void gemm1_mfma(
    const float* __restrict__ x, const ushort* __restrict__ wpack,
    float* __restrict__ hp1, float* __restrict__ p2, int N)
{
    __shared__ __align__(16) ushort a_lds[2][64 * 32];   // 4 KB per buffer
    const int tid = threadIdx.x;
    const int lane = tid & 63;
    const int wc = tid >> 6;            // wave id -> col group
    const int rowbase = blockIdx.x * 64;

    // staging: thread -> (row = tid>>2, kg = tid&3), one 8-elem chunk
    const int srow = tid >> 2;
    const int skg = tid & 3;
    const int sgr = rowbase + srow;
    const int sidx = ((srow >> 4) * 64 + skg * 16 + (srow & 15)) * 8;

    f32x4 acc[4][2];
#pragma unroll
    for (int i = 0; i < 4; i++)
#pragma unroll
        for (int j = 0; j < 2; j++) acc[i][j] = (f32x4){0.f, 0.f, 0.f, 0.f};

    float4 s0, s1;
    auto load_stage = [&](int t) {
        int k0 = t * 32 + skg * 8;
        s0 = make_float4(0.f, 0.f, 0.f, 0.f);
        s1 = make_float4(0.f, 0.f, 0.f, 0.f);
        if (sgr < N && k0 + 8 <= DIM_IN) {
            const float* p = &x[(size_t)sgr * DIM_IN + k0];
            s0 = *(const float4*)p;
            s1 = *(const float4*)(p + 4);
        }
    };
    auto store_stage = [&](int buf) {
        uint4 w;
        w.x = pack2(s0.x, s0.y);
        w.y = pack2(s0.z, s0.w);
        w.z = pack2(s1.x, s1.y);
        w.w = pack2(s1.z, s1.w);
        *(uint4*)&a_lds[buf][sidx] = w;
    };

    load_stage(0);
    store_stage(0);
    __syncthreads();

    const s16x8* wp = (const s16x8*)wpack;
    for (int t = 0; t < 32; t++) {
        int cur = t & 1;
        if (t + 1 < 32) load_stage(t + 1);        // global prefetch (hidden under MFMA)
        // B fragments (global, fragment-ordered): ct_global = wc*2 + ctl
        s16x8 bf0 = wp[(size_t)(t * 8 + wc * 2 + 0) * 64 + lane];
        s16x8 bf1 = wp[(size_t)(t * 8 + wc * 2 + 1) * 64 + lane];
        // A fragments (LDS, stride-1 b128)
        s16x8 af0 = *(const s16x8*)&a_lds[cur][(0 * 64 + lane) * 8];
        s16x8 af1 = *(const s16x8*)&a_lds[cur][(1 * 64 + lane) * 8];
        s16x8 af2 = *(const s16x8*)&a_lds[cur][(2 * 64 + lane) * 8];
        s16x8 af3 = *(const s16x8*)&a_lds[cur][(3 * 64 + lane) * 8];
        acc[0][0] = __builtin_amdgcn_mfma_f32_16x16x32_bf16(af0, bf0, acc[0][0], 0, 0, 0);
        acc[0][1] = __builtin_amdgcn_mfma_f32_16x16x32_bf16(af0, bf1, acc[0][1], 0, 0, 0);
        acc[1][0] = __builtin_amdgcn_mfma_f32_16x16x32_bf16(af1, bf0, acc[1][0], 0, 0, 0);
        acc[1][1] = __builtin_amdgcn_mfma_f32_16x16x32_bf16(af1, bf1, acc[1][1], 0, 0, 0);
        acc[2][0] = __builtin_amdgcn_mfma_f32_16x16x32_bf16(af2, bf0, acc[2][0], 0, 0, 0);
        acc[2][1] = __builtin_amdgcn_mfma_f32_16x16x32_bf16(af2, bf1, acc[2][1], 0, 0, 0);
        acc[3][0] = __builtin_amdgcn_mfma_f32_16x16x32_bf16(af3, bf0, acc[3][0], 0, 0, 0);
        acc[3][1] = __builtin_amdgcn_mfma_f32_16x16x32_bf16(af3, bf1, acc[3][1], 0, 0, 0);
        if (t + 1 < 32) store_stage(cur ^ 1);     // write next tile to other buffer
        __syncthreads();
    }

    // epilogue: C/D mapping col=lane&15, row=(lane>>4)*4+reg  [m89-verified]
    const int colbase = wc * 32;
#pragma unroll
    for (int rt = 0; rt < 4; rt++) {
        int gr = rowbase + rt * 16 + ((lane >> 4) * 4);
#pragma unroll
        for (int ctl = 0; ctl < 2; ctl++) {
            int c = colbase + ctl * 16 + (lane & 15);
            float* dst = (c < 64) ? hp1 : p2;
            int cc = (c < 64) ? c : c - 64;
#pragma unroll
            for (int reg = 0; reg < 4; reg++) {
                int r = gr + reg;
                if (r < N) dst[(size_t)r * 64 + cc] = acc[rt][ctl][reg];
            }
        }
    }
}

// ---------------- small GEMM, K=64, NC=64, out += A@W ----------------
__global__ __launch_bounds__(256) void gemm_k64_n64_acc(
    const float* __restrict__ A, const float* __restrict__ W,
    float* __restrict__ out, int N)
{
    __shared__ float as_[16][65];
    const int tid = threadIdx.x;
    const int rb = blockIdx.x * 16;
#pragma unroll
    for (int i = 0; i < 4; i++) {
        int idx = tid + i * 256;
        int r = idx >> 6, c = idx & 63;
        int gr = rb + r;
        as_[r][c] = (gr < N) ? A[(size_t)gr * 64 + c] : 0.f;
    }
    __syncthreads();
    const int row = tid >> 4;
    const int col = (tid & 15) * 4;
    float4 acc = {0, 0, 0, 0};
#pragma unroll 8
    for (int k = 0; k < 64; k++) {
        float a = as_[row][k];
        float4 w = *(const float4*)&W[k * 64 + col];
        acc.x += a * w.x; acc.y += a * w.y; acc.z += a * w.z; acc.w += a * w.w;
    }
    int gr = rb + row;
    if (gr < N) {
        float* o = &out[(size_t)gr * 64 + col];
        o[0] += acc.x; o[1] += acc.y; o[2] += acc.z; o[3] += acc.w;
    }
}

// ---------------- attention dots (per-head h layout [N,H,C]) ----------------
template <int C>
__global__ __launch_bounds__(256) void attn_dots(
    const float* __restrict__ h, const float* __restrict__ a_s,
    const float* __restrict__ a_d, float* __restrict__ als,
    float* __restrict__ ald, int NH)
{
    int i = blockIdx.x * blockDim.x + threadIdx.x;  // node*8 + head
    if (i >= NH) return;
    int head = i & 7;
    const float* hp = h + (size_t)i * C;
    float s = 0.f, d = 0.f;
#pragma unroll
    for (int c = 0; c < C; c++) {
        float v = hp[c];
        s += v * a_s[head * C + c];
        d += v * a_d[head * C + c];
    }
    als[i] = s; ald[i] = d;
}

// ---------------- layer-3 attention dots from h2 via wtilde ----------------
__global__ __launch_bounds__(512) void make_wtilde(
    const float* __restrict__ W3, const float* __restrict__ as3,
    const float* __restrict__ ad3, float* __restrict__ wts,
    float* __restrict__ wtd)
{
    int t = threadIdx.x;          // 512 = 8 heads x 64 k
    int h = t >> 6, k = t & 63;
    float s = 0.f, d = 0.f;
#pragma unroll
    for (int c = 0; c < 32; c++) {
        float w = W3[(size_t)k * 256 + h * 32 + c];
        s += w * as3[h * 32 + c];
        d += w * ad3[h * 32 + c];
    }
    wts[h * 64 + k] = s;
    wtd[h * 64 + k] = d;
}

__global__ __launch_bounds__(256) void attn_dots_w(
    const float* __restrict__ h2, const float* __restrict__ wts,
    const float* __restrict__ wtd, float* __restrict__ als,
    float* __restrict__ ald, int NH)
{
    int i = blockIdx.x * blockDim.x + threadIdx.x;  // node*8 + head
    if (i >= NH) return;
    int head = i & 7, node = i >> 3;
    const float* hp = h2 + (size_t)node * 64;
    float s = 0.f, d = 0.f;
#pragma unroll
    for (int c = 0; c < 64; c++) {
        float v = hp[c];
        s += v * wts[head * 64 + c];
        d += v * wtd[head * 64 + c];
    }
    als[i] = s; ald[i] = d;
}

// ---------------- CSR build ----------------
__global__ __launch_bounds__(256) void csr_hist(
    const int* __restrict__ ei, int E, int Etot, int* __restrict__ deg)
{
    int e = blockIdx.x * blockDim.x + threadIdx.x;
    if (e >= Etot) return;
    int d = (e < E) ? ei[E + e] : e - E;
    atomicAdd(&deg[d], 1);
}

__global__ __launch_bounds__(1024) void csr_scan(
    const int* __restrict__ deg, int* __restrict__ rowptr,
    int* __restrict__ cursor, int N)
{
    __shared__ int partial[1024];
    const int t = threadIdx.x;
    const int chunk = (N + 1023) >> 10;
    const int lo = t * chunk;
    const int hi = min(N, lo + chunk);
    int s = 0;
    for (int i = lo; i < hi; i++) s += deg[i];
    partial[t] = s;
    __syncthreads();
    for (int off = 1; off < 1024; off <<= 1) {
        int v = (t >= off) ? partial[t - off] : 0;
        __syncthreads();
        partial[t] += v;
        __syncthreads();
    }
    int run = (t == 0) ? 0 : partial[t - 1];
    for (int i = lo; i < hi; i++) {
        rowptr[i] = run;
        cursor[i] = run;
        run += deg[i];
    }
    if (t == 1023) rowptr[N] = partial[1023];
}

__global__ __launch_bounds__(256) void csr_fill(
    const int* __restrict__ ei, int E, int Etot,
    int* __restrict__ cursor, int* __restrict__ esrc)
{
    int e = blockIdx.x * blockDim.x + threadIdx.x;
    if (e >= Etot) return;
    int s, d;
    if (e < E) { s = ei[e]; d = ei[E + e]; } else { s = d = e - E; }
    int pos = atomicAdd(&cursor[d], 1);
    esrc[pos] = s;
}

// ---------------- fused gather layer (C=64): online softmax + bias + ELU ----------------
__global__ __launch_bounds__(256) void gat_gather64(
    const int* __restrict__ rowptr, const int* __restrict__ esrc,
    const float* __restrict__ als, const float* __restrict__ ald,
    const float* __restrict__ h, const float* __restrict__ bias,
    float* __restrict__ out, int N)
{
    int node = blockIdx.x * 4 + (threadIdx.x >> 6);
    if (node >= N) return;
    int lane = threadIdx.x & 63;
    int head = lane >> 3;
    int start = rowptr[node], end = rowptr[node + 1];
    float aldv = ald[(size_t)node * 8 + head];
    float m = -1e30f, den = 0.f, acc = 0.f;
    for (int i = start; i < end; i++) {
        int s = esrc[i];
        float e = als[(size_t)s * 8 + head] + aldv;
        e = (e > 0.f) ? e : NEG_SLOPE * e;
        float hv = h[(size_t)s * 64 + lane];
        float nm = fmaxf(m, e);
        float sc = __expf(m - nm);
        float ee = __expf(e - nm);
        acc = acc * sc + ee * hv;
        den = den * sc + ee;
        m = nm;
    }
    float v = acc / (den + 1e-16f) + bias[lane];
    out[(size_t)node * 64 + lane] = (v > 0.f) ? v : (__expf(v) - 1.f);
}

// ---------------- layer 3 fully fused: gather h2 (per-head), tiny GEMM with W3,
// head-mean, bias, log_softmax. One wave per node. ----------------
__global__ __launch_bounds__(256) void gat_l3_final(
    const int* __restrict__ rowptr, const int* __restrict__ esrc,
    const float* __restrict__ als, const float* __restrict__ ald,
    const float* __restrict__ h2, const float* __restrict__ W3,
    const float* __restrict__ b3, float* __restrict__ out, int N)
{
    int node = blockIdx.x * 4 + (threadIdx.x >> 6);
    if (node >= N) return;
    int lane = threadIdx.x & 63;
    int h = lane >> 3, c8 = lane & 7;
    int start = rowptr[node], end = rowptr[node + 1];
    float aldv = ald[(size_t)node * 8 + h];
    float m = -1e30f, den = 0.f;
    float acc[8] = {};
    for (int i = start; i < end; i++) {
        int s = esrc[i];
        float e = als[(size_t)s * 8 + h] + aldv;
        e = (e > 0.f) ? e : NEG_SLOPE * e;
        float4 hv0 = *(const float4*)&h2[(size_t)s * 64 + c8 * 8];
        float4 hv1 = *(const float4*)&h2[(size_t)s * 64 + c8 * 8 + 4];
        float nm = fmaxf(m, e);
        float sc = __expf(m - nm);
        float ee = __expf(e - nm);
        acc[0] = acc[0] * sc + ee * hv0.x;
        acc[1] = acc[1] * sc + ee * hv0.y;
        acc[2] = acc[2] * sc + ee * hv0.z;
        acc[3] = acc[3] * sc + ee * hv0.w;
        acc[4] = acc[4] * sc + ee * hv1.x;
        acc[5] = acc[5] * sc + ee * hv1.y;
        acc[6] = acc[6] * sc + ee * hv1.z;
        acc[7] = acc[7] * sc + ee * hv1.w;
        den = den * sc + ee;
        m = nm;
    }
    float inv = 1.f / (den + 1e-16f);
#pragma unroll
    for (int j = 0; j < 8; j++) acc[j] *= inv;

    // tiny GEMM: out[h, c8*4..+3] = sum_k agg[h][k] * W3[k][h*32+c8*4..]
    float4 o4 = {0.f, 0.f, 0.f, 0.f};
#pragma unroll
    for (int r = 0; r < 8; r++) {
#pragma unroll
        for (int j = 0; j < 8; j++) {
            float a = __shfl(acc[j], h * 8 + r, 64);
            int k = r * 8 + j;
            float4 w = *(const float4*)&W3[(size_t)k * 256 + h * 32 + c8 * 4];
            o4.x += a * w.x; o4.y += a * w.y; o4.z += a * w.z; o4.w += a * w.w;
        }
    }
    // head-mean across lanes c8, 8+c8, ..., 56+c8
#pragma unroll
    for (int o = 8; o < 64; o <<= 1) {
        o4.x += __shfl_xor(o4.x, o, 64);
        o4.y += __shfl_xor(o4.y, o, 64);
        o4.z += __shfl_xor(o4.z, o, 64);
        o4.w += __shfl_xor(o4.w, o, 64);
    }
    int cq = c8 * 4;
    o4.x = o4.x * 0.125f + b3[cq + 0];
    o4.y = o4.y * 0.125f + b3[cq + 1];
    o4.z = o4.z * 0.125f + b3[cq + 2];
    o4.w = o4.w * 0.125f + b3[cq + 3];
    float mx = fmaxf(fmaxf(o4.x, o4.y), fmaxf(o4.z, o4.w));
#pragma unroll
    for (int o = 1; o < 8; o <<= 1) mx = fmaxf(mx, __shfl_xor(mx, o, 64));
    float ex = __expf(o4.x - mx) + __expf(o4.y - mx) + __expf(o4.z - mx) + __expf(o4.w - mx);
#pragma unroll
    for (int o = 1; o < 8; o <<= 1) ex += __shfl_xor(ex, o, 64);
    float lse = mx + __logf(ex);
    if (lane < 8) {
        float4 r4 = {o4.x - lse, o4.y - lse, o4.z - lse, o4.w - lse};
        *(float4*)&out[(size_t)node * 32 + cq] = r4;
    }
}

// ---------------- host launch ----------------
extern "C" void kernel_launch(void* const* d_in, const int* in_sizes, int n_in,
                              void* d_out, int out_size, void* d_ws, size_t ws_size,
                              hipStream_t stream)
{
    const float* x   = (const float*)d_in[0];
    const int*   ei  = (const int*)  d_in[1];
    const float* W1  = (const float*)d_in[2];
    const float* as1 = (const float*)d_in[3];
    const float* ad1 = (const float*)d_in[4];
    const float* b1  = (const float*)d_in[5];
    const float* W2  = (const float*)d_in[6];
    const float* as2 = (const float*)d_in[7];
    const float* ad2 = (const float*)d_in[8];
    const float* b2  = (const float*)d_in[9];
    const float* W3  = (const float*)d_in[10];
    const float* as3 = (const float*)d_in[11];
    const float* ad3 = (const float*)d_in[12];
    const float* b3  = (const float*)d_in[13];
    float* out = (float*)d_out;

    const int N = in_sizes[0] / DIM_IN;
    const int E = in_sizes[1] / 2;
    const int Etot = E + N;

    float* ws = (float*)d_ws;
    size_t o = 0;
    float* hp1 = ws + o; o += (size_t)N * 64;    // x@W1
    float* p2  = ws + o; o += (size_t)N * 64;    // x@W2a, then h2pre
    float* h1  = ws + o; o += (size_t)N * 64;
    float* h2  = ws + o; o += (size_t)N * 64;
    float* als = ws + o; o += (size_t)N * 8;
    float* ald = ws + o; o += (size_t)N * 8;
    float* wts = ws + o; o += 512;
    float* wtd = ws + o; o += 512;
    ushort* wpack = (ushort*)(ws + o); o += 32768;   // 32*8*64*8 ushorts
    int* deg    = (int*)(ws + o); o += N;
    int* rowptr = (int*)(ws + o); o += N + 1;
    int* cursor = (int*)(ws + o); o += N;
    int* esrc   = (int*)(ws + o); o += Etot;
    if (o * 4 > ws_size) return;  // workspace too small -> visible failure

    const int TB = 256;

    // W pre-pack + fused MFMA GEMM over x: hp1 = x@W1, p2 = x@W2[:1000]
    pack_w<<<64, TB, 0, stream>>>(W1, W2, wpack);
    gemm1_mfma<<<(N + 63) / 64, TB, 0, stream>>>(x, wpack, hp1, p2, N);

    // CSR build (graph shared by all 3 layers)
    hipMemsetAsync(deg, 0, (size_t)N * 4, stream);
    csr_hist<<<(Etot + TB - 1) / TB, TB, 0, stream>>>(ei, E, Etot, deg);
    csr_scan<<<1, 1024, 0, stream>>>(deg, rowptr, cursor, N);
    csr_fill<<<(Etot + TB - 1) / TB, TB, 0, stream>>>(ei, E, Etot, cursor, esrc);

    // ---- layer 1 ----
    attn_dots<8><<<(N * 8 + TB - 1) / TB, TB, 0, stream>>>(hp1, as1, ad1, als, ald, N * 8);
    gat_gather64<<<(N + 3) / 4, TB, 0, stream>>>(rowptr, esrc, als, ald, hp1, b1, h1, N);

    // p2 += h1 @ W2[1000:1064]  -> h2pre
    gemm_k64_n64_acc<<<(N + 15) / 16, TB, 0, stream>>>(h1, W2 + (size_t)DIM_IN * 64, p2, N);

    // ---- layer 2 ----
    attn_dots<8><<<(N * 8 + TB - 1) / TB, TB, 0, stream>>>(p2, as2, ad2, als, ald, N * 8);
    gat_gather64<<<(N + 3) / 4, TB, 0, stream>>>(rowptr, esrc, als, ald, p2, b2, h2, N);

    // ---- layer 3 (restructured: aggregate h2, then tiny per-head GEMM) ----
    make_wtilde<<<1, 512, 0, stream>>>(W3, as3, ad3, wts, wtd);
    attn_dots_w<<<(N * 8 + TB - 1) / TB, TB, 0, stream>>>(h2, wts, wtd, als, ald, N * 8);
    gat_l3_final<<<(N + 3) / 4, TB, 0, stream>>>(rowptr, esrc, als, ald, h2, W3, b3, out, N);
}

// Round 6
// 609.545 us; speedup vs baseline: 1.4395x; 1.0929x over previous
//
#include <hip/hip_runtime.h>
#include <hip/hip_bf16.h>

// ---------------- constants (match reference) ----------------
#define DIM_IN 1000
#define HEADS 8
#define HID 8
#define DIM_OUT 32
#define NEG_SLOPE 0.2f
#define RESCALE_THR 8.f

typedef __attribute__((ext_vector_type(4))) float f32x4;
typedef __attribute__((ext_vector_type(8))) short s16x8;

__device__ __forceinline__ unsigned bf16rne(float f) {
    unsigned u = __float_as_uint(f);
    return (u + 0x7FFFu + ((u >> 16) & 1u)) >> 16;
}
__device__ __forceinline__ unsigned pack2(float lo, float hi) {
    return bf16rne(lo) | (bf16rne(hi) << 16);
}

// ---------------- W pre-pack: fragment-ordered bf16 [32 kt][8 ctg][64 lane][8] ----
__global__ __launch_bounds__(256) void pack_w(
    const float* __restrict__ W1, const float* __restrict__ W2,
    ushort* __restrict__ wpack)
{
    int t = blockIdx.x * 256 + threadIdx.x;   // 0..16383
    if (t >= 32 * 8 * 64) return;
    int lane = t & 63;
    int ctg = (t >> 6) & 7;
    int kt = t >> 9;
    int c = ctg * 16 + (lane & 15);
    int kbase = kt * 32 + (lane >> 4) * 8;
    ushort v[8] __attribute__((aligned(16)));
#pragma unroll
    for (int j = 0; j < 8; j++) {
        int k = kbase + j;
        float w = 0.f;
        if (k < DIM_IN) w = (c < 64) ? W1[(size_t)k * 64 + c] : W2[(size_t)k * 64 + (c - 64)];
        v[j] = (ushort)bf16rne(w);
    }
    *(uint4*)&wpack[(size_t)t * 8] = *(const uint4*)v;
}

// ---------------- GEMM1 (MFMA bf16): [N,128] = x[N,1000] @ [W1 | W2a] ----------------
__global__ __launch_bounds__(256) void gemm1_mfma(
    const float* __restrict__ x, const ushort* __restrict__ wpack,
    float* __restrict__ hp1, float* __restrict__ p2, int N)
{
    __shared__ __align__(16) ushort a_lds[2][64 * 32];
    const int tid = threadIdx.x;
    const int lane = tid & 63;
    const int wc = tid >> 6;
    const int rowbase = blockIdx.x * 64;

    const int srow = tid >> 2;
    const int skg = tid & 3;
    const int sgr = rowbase + srow;
    const int sidx = ((srow >> 4) * 64 + skg * 16 + (srow & 15)) * 8;

    f32x4 acc[4][2];
#pragma unroll
    for (int i = 0; i < 4; i++)
#pragma unroll
        for (int j = 0; j < 2; j++) acc[i][j] = (f32x4){0.f, 0.f, 0.f, 0.f};

    float4 s0, s1;
    auto load_stage = [&](int t) {
        int k0 = t * 32 + skg * 8;
        s0 = make_float4(0.f, 0.f, 0.f, 0.f);
        s1 = make_float4(0.f, 0.f, 0.f, 0.f);
        if (sgr < N && k0 + 8 <= DIM_IN) {
            const float* p = &x[(size_t)sgr * DIM_IN + k0];
            s0 = *(const float4*)p;
            s1 = *(const float4*)(p + 4);
        }
    };
    auto store_stage = [&](int buf) {
        uint4 w;
        w.x = pack2(s0.x, s0.y);
        w.y = pack2(s0.z, s0.w);
        w.z = pack2(s1.x, s1.y);
        w.w = pack2(s1.z, s1.w);
        *(uint4*)&a_lds[buf][sidx] = w;
    };

    load_stage(0);
    store_stage(0);
    __syncthreads();

    const s16x8* wp = (const s16x8*)wpack;
    for (int t = 0; t < 32; t++) {
        int cur = t & 1;
        if (t + 1 < 32) load_stage(t + 1);
        s16x8 bf0 = wp[(size_t)(t * 8 + wc * 2 + 0) * 64 + lane];
        s16x8 bf1 = wp[(size_t)(t * 8 + wc * 2 + 1) * 64 + lane];
        s16x8 af0 = *(const s16x8*)&a_lds[cur][(0 * 64 + lane) * 8];
        s16x8 af1 = *(const s16x8*)&a_lds[cur][(1 * 64 + lane) * 8];
        s16x8 af2 = *(const s16x8*)&a_lds[cur][(2 * 64 + lane) * 8];
        s16x8 af3 = *(const s16x8*)&a_lds[cur][(3 * 64 + lane) * 8];
        acc[0][0] = __builtin_amdgcn_mfma_f32_16x16x32_bf16(af0, bf0, acc[0][0], 0, 0, 0);
        acc[0][1] = __builtin_amdgcn_mfma_f32_16x16x32_bf16(af0, bf1, acc[0][1], 0, 0, 0);
        acc[1][0] = __builtin_amdgcn_mfma_f32_16x16x32_bf16(af1, bf0, acc[1][0], 0, 0, 0);
        acc[1][1] = __builtin_amdgcn_mfma_f32_16x16x32_bf16(af1, bf1, acc[1][1], 0, 0, 0);
        acc[2][0] = __builtin_amdgcn_mfma_f32_16x16x32_bf16(af2, bf0, acc[2][0], 0, 0, 0);
        acc[2][1] = __builtin_amdgcn_mfma_f32_16x16x32_bf16(af2, bf1, acc[2][1], 0, 0, 0);
        acc[3][0] = __builtin_amdgcn_mfma_f32_16x16x32_bf16(af3, bf0, acc[3][0], 0, 0, 0);
        acc[3][1] = __builtin_amdgcn_mfma_f32_16x16x32_bf16(af3, bf1, acc[3][1], 0, 0, 0);
        if (t + 1 < 32) store_stage(cur ^ 1);
        __syncthreads();
    }

    const int colbase = wc * 32;
#pragma unroll
    for (int rt = 0; rt < 4; rt++) {
        int gr = rowbase + rt * 16 + ((lane >> 4) * 4);
#pragma unroll
        for (int ctl = 0; ctl < 2; ctl++) {
            int c = colbase + ctl * 16 + (lane & 15);
            float* dst = (c < 64) ? hp1 : p2;
            int cc = (c < 64) ? c : c - 64;
#pragma unroll
            for (int reg = 0; reg < 4; reg++) {
                int r = gr + reg;
                if (r < N) dst[(size_t)r * 64 + cc] = acc[rt][ctl][reg];
            }
        }
    }
}

// ---------------- small GEMM, K=64, NC=64, out += A@W ----------------
__global__ __launch_bounds__(256) void gemm_k64_n64_acc(
    const float* __restrict__ A, const float* __restrict__ W,
    float* __restrict__ out, int N)
{
    __shared__ float as_[16][65];
    const int tid = threadIdx.x;
    const int rb = blockIdx.x * 16;
#pragma unroll
    for (int i = 0; i < 4; i++) {
        int idx = tid + i * 256;
        int r = idx >> 6, c = idx & 63;
        int gr = rb + r;
        as_[r][c] = (gr < N) ? A[(size_t)gr * 64 + c] : 0.f;
    }
    __syncthreads();
    const int row = tid >> 4;
    const int col = (tid & 15) * 4;
    float4 acc = {0, 0, 0, 0};
#pragma unroll 8
    for (int k = 0; k < 64; k++) {
        float a = as_[row][k];
        float4 w = *(const float4*)&W[k * 64 + col];
        acc.x += a * w.x; acc.y += a * w.y; acc.z += a * w.z; acc.w += a * w.w;
    }
    int gr = rb + row;
    if (gr < N) {
        float* o = &out[(size_t)gr * 64 + col];
        o[0] += acc.x; o[1] += acc.y; o[2] += acc.z; o[3] += acc.w;
    }
}

// ---------------- attention dots (per-head h layout [N,H,C]) ----------------
template <int C>
__global__ __launch_bounds__(256) void attn_dots(
    const float* __restrict__ h, const float* __restrict__ a_s,
    const float* __restrict__ a_d, float* __restrict__ als,
    float* __restrict__ ald, int NH)
{
    int i = blockIdx.x * blockDim.x + threadIdx.x;
    if (i >= NH) return;
    int head = i & 7;
    const float* hp = h + (size_t)i * C;
    float s = 0.f, d = 0.f;
#pragma unroll
    for (int c = 0; c < C; c++) {
        float v = hp[c];
        s += v * a_s[head * C + c];
        d += v * a_d[head * C + c];
    }
    als[i] = s; ald[i] = d;
}

// ---------------- layer-3 attention dots from h2 via wtilde ----------------
__global__ __launch_bounds__(512) void make_wtilde(
    const float* __restrict__ W3, const float* __restrict__ as3,
    const float* __restrict__ ad3, float* __restrict__ wts,
    float* __restrict__ wtd)
{
    int t = threadIdx.x;
    int h = t >> 6, k = t & 63;
    float s = 0.f, d = 0.f;
#pragma unroll
    for (int c = 0; c < 32; c++) {
        float w = W3[(size_t)k * 256 + h * 32 + c];
        s += w * as3[h * 32 + c];
        d += w * ad3[h * 32 + c];
    }
    wts[h * 64 + k] = s;
    wtd[h * 64 + k] = d;
}

__global__ __launch_bounds__(256) void attn_dots_w(
    const float* __restrict__ h2, const float* __restrict__ wts,
    const float* __restrict__ wtd, float* __restrict__ als,
    float* __restrict__ ald, int NH)
{
    int i = blockIdx.x * blockDim.x + threadIdx.x;
    if (i >= NH) return;
    int head = i & 7, node = i >> 3;
    const float* hp = h2 + (size_t)node * 64;
    float s = 0.f, d = 0.f;
#pragma unroll
    for (int c = 0; c < 64; c++) {
        float v = hp[c];
        s += v * wts[head * 64 + c];
        d += v * wtd[head * 64 + c];
    }
    als[i] = s; ald[i] = d;
}

// ---------------- CSR build ----------------
__global__ __launch_bounds__(256) void csr_hist(
    const int* __restrict__ ei, int E, int Etot, int* __restrict__ deg)
{
    int e = blockIdx.x * blockDim.x + threadIdx.x;
    if (e >= Etot) return;
    int d = (e < E) ? ei[E + e] : e - E;
    atomicAdd(&deg[d], 1);
}

__global__ __launch_bounds__(1024) void csr_scan(
    const int* __restrict__ deg, int* __restrict__ rowptr,
    int* __restrict__ cursor, int N)
{
    __shared__ int partial[1024];
    const int t = threadIdx.x;
    const int chunk = (N + 1023) >> 10;
    const int lo = t * chunk;
    const int hi = min(N, lo + chunk);
    int s = 0;
    for (int i = lo; i < hi; i++) s += deg[i];
    partial[t] = s;
    __syncthreads();
    for (int off = 1; off < 1024; off <<= 1) {
        int v = (t >= off) ? partial[t - off] : 0;
        __syncthreads();
        partial[t] += v;
        __syncthreads();
    }
    int run = (t == 0) ? 0 : partial[t - 1];
    for (int i = lo; i < hi; i++) {
        rowptr[i] = run;
        cursor[i] = run;
        run += deg[i];
    }
    if (t == 1023) rowptr[N] = partial[1023];
}

__global__ __launch_bounds__(256) void csr_fill(
    const int* __restrict__ ei, int E, int Etot,
    int* __restrict__ cursor, int* __restrict__ esrc)
{
    int e = blockIdx.x * blockDim.x + threadIdx.x;
    if (e >= Etot) return;
    int s, d;
    if (e < E) { s = ei[e]; d = ei[E + e]; } else { s = d = e - E; }
    int pos = atomicAdd(&cursor[d], 1);
    esrc[pos] = s;
}

// ---------------- fused gather layer (C=64): 2-stream online softmax + defer-max
// + bias + ELU ----------------
__global__ __launch_bounds__(256) void gat_gather64(
    const int* __restrict__ rowptr, const int* __restrict__ esrc,
    const float* __restrict__ als, const float* __restrict__ ald,
    const float* __restrict__ h, const float* __restrict__ bias,
    float* __restrict__ out, int N)
{
    int node = blockIdx.x * 4 + (threadIdx.x >> 6);
    if (node >= N) return;
    int lane = threadIdx.x & 63;
    int head = lane >> 3;
    int start = rowptr[node], end = rowptr[node + 1];
    float aldv = ald[(size_t)node * 8 + head];
    float mA = -1e30f, dA = 0.f, aA = 0.f;
    float mB = -1e30f, dB = 0.f, aB = 0.f;

    int i = start;
    for (; i + 1 < end; i += 2) {
        int s0 = esrc[i], s1 = esrc[i + 1];
        float e0 = als[(size_t)s0 * 8 + head] + aldv;
        float e1 = als[(size_t)s1 * 8 + head] + aldv;
        float hv0 = h[(size_t)s0 * 64 + lane];
        float hv1 = h[(size_t)s1 * 64 + lane];
        e0 = (e0 > 0.f) ? e0 : NEG_SLOPE * e0;
        e1 = (e1 > 0.f) ? e1 : NEG_SLOPE * e1;
        if (__any(e0 - mA > RESCALE_THR)) {
            float nm = fmaxf(mA, e0), sc = __expf(mA - nm);
            aA *= sc; dA *= sc; mA = nm;
        }
        float ee0 = __expf(e0 - mA);
        dA += ee0; aA = fmaf(ee0, hv0, aA);
        if (__any(e1 - mB > RESCALE_THR)) {
            float nm = fmaxf(mB, e1), sc = __expf(mB - nm);
            aB *= sc; dB *= sc; mB = nm;
        }
        float ee1 = __expf(e1 - mB);
        dB += ee1; aB = fmaf(ee1, hv1, aB);
    }
    if (i < end) {
        int s0 = esrc[i];
        float e0 = als[(size_t)s0 * 8 + head] + aldv;
        float hv0 = h[(size_t)s0 * 64 + lane];
        e0 = (e0 > 0.f) ? e0 : NEG_SLOPE * e0;
        if (__any(e0 - mA > RESCALE_THR)) {
            float nm = fmaxf(mA, e0), sc = __expf(mA - nm);
            aA *= sc; dA *= sc; mA = nm;
        }
        float ee0 = __expf(e0 - mA);
        dA += ee0; aA = fmaf(ee0, hv0, aA);
    }
    float m = fmaxf(mA, mB);
    float sA = __expf(mA - m), sB = __expf(mB - m);
    float den = dA * sA + dB * sB;
    float acc = aA * sA + aB * sB;
    float v = acc / (den + 1e-16f) + bias[lane];
    out[(size_t)node * 64 + lane] = (v > 0.f) ? v : (__expf(v) - 1.f);
}

// ---------------- layer 3 fully fused: 2-stream gather of h2 + defer-max,
// tiny per-head GEMM with W3, head-mean, bias, log_softmax ----------------
__global__ __launch_bounds__(256) void gat_l3_final(
    const int* __restrict__ rowptr, const int* __restrict__ esrc,
    const float* __restrict__ als, const float* __restrict__ ald,
    const float* __restrict__ h2, const float* __restrict__ W3,
    const float* __restrict__ b3, float* __restrict__ out, int N)
{
    int node = blockIdx.x * 4 + (threadIdx.x >> 6);
    if (node >= N) return;
    int lane = threadIdx.x & 63;
    int h = lane >> 3, c8 = lane & 7;
    int start = rowptr[node], end = rowptr[node + 1];
    float aldv = ald[(size_t)node * 8 + h];
    float mA = -1e30f, dA = 0.f;
    float mB = -1e30f, dB = 0.f;
    float accA[8] = {}, accB[8] = {};

    int i = start;
    for (; i + 1 < end; i += 2) {
        int s0 = esrc[i], s1 = esrc[i + 1];
        float e0 = als[(size_t)s0 * 8 + h] + aldv;
        float e1 = als[(size_t)s1 * 8 + h] + aldv;
        float4 u0 = *(const float4*)&h2[(size_t)s0 * 64 + c8 * 8];
        float4 v0 = *(const float4*)&h2[(size_t)s0 * 64 + c8 * 8 + 4];
        float4 u1 = *(const float4*)&h2[(size_t)s1 * 64 + c8 * 8];
        float4 v1 = *(const float4*)&h2[(size_t)s1 * 64 + c8 * 8 + 4];
        e0 = (e0 > 0.f) ? e0 : NEG_SLOPE * e0;
        e1 = (e1 > 0.f) ? e1 : NEG_SLOPE * e1;
        if (__any(e0 - mA > RESCALE_THR)) {
            float nm = fmaxf(mA, e0), sc = __expf(mA - nm);
            dA *= sc;
#pragma unroll
            for (int j = 0; j < 8; j++) accA[j] *= sc;
            mA = nm;
        }
        float ee0 = __expf(e0 - mA);
        dA += ee0;
        accA[0] = fmaf(ee0, u0.x, accA[0]); accA[1] = fmaf(ee0, u0.y, accA[1]);
        accA[2] = fmaf(ee0, u0.z, accA[2]); accA[3] = fmaf(ee0, u0.w, accA[3]);
        accA[4] = fmaf(ee0, v0.x, accA[4]); accA[5] = fmaf(ee0, v0.y, accA[5]);
        accA[6] = fmaf(ee0, v0.z, accA[6]); accA[7] = fmaf(ee0, v0.w, accA[7]);
        if (__any(e1 - mB > RESCALE_THR)) {
            float nm = fmaxf(mB, e1), sc = __expf(mB - nm);
            dB *= sc;
#pragma unroll
            for (int j = 0; j < 8; j++) accB[j] *= sc;
            mB = nm;
        }
        float ee1 = __expf(e1 - mB);
        dB += ee1;
        accB[0] = fmaf(ee1, u1.x, accB[0]); accB[1] = fmaf(ee1, u1.y, accB[1]);
        accB[2] = fmaf(ee1, u1.z, accB[2]); accB[3] = fmaf(ee1, u1.w, accB[3]);
        accB[4] = fmaf(ee1, v1.x, accB[4]); accB[5] = fmaf(ee1, v1.y, accB[5]);
        accB[6] = fmaf(ee1, v1.z, accB[6]); accB[7] = fmaf(ee1, v1.w, accB[7]);
    }
    if (i < end) {
        int s0 = esrc[i];
        float e0 = als[(size_t)s0 * 8 + h] + aldv;
        float4 u0 = *(const float4*)&h2[(size_t)s0 * 64 + c8 * 8];
        float4 v0 = *(const float4*)&h2[(size_t)s0 * 64 + c8 * 8 + 4];
        e0 = (e0 > 0.f) ? e0 : NEG_SLOPE * e0;
        if (__any(e0 - mA > RESCALE_THR)) {
            float nm = fmaxf(mA, e0), sc = __expf(mA - nm);
            dA *= sc;
#pragma unroll
            for (int j = 0; j < 8; j++) accA[j] *= sc;
            mA = nm;
        }
        float ee0 = __expf(e0 - mA);
        dA += ee0;
        accA[0] = fmaf(ee0, u0.x, accA[0]); accA[1] = fmaf(ee0, u0.y, accA[1]);
        accA[2] = fmaf(ee0, u0.z, accA[2]); accA[3] = fmaf(ee0, u0.w, accA[3]);
        accA[4] = fmaf(ee0, v0.x, accA[4]); accA[5] = fmaf(ee0, v0.y, accA[5]);
        accA[6] = fmaf(ee0, v0.z, accA[6]); accA[7] = fmaf(ee0, v0.w, accA[7]);
    }

    float mm = fmaxf(mA, mB);
    float sA = __expf(mA - mm), sB = __expf(mB - mm);
    float den = dA * sA + dB * sB;
    float acc[8];
#pragma unroll
    for (int j = 0; j < 8; j++) acc[j] = accA[j] * sA + accB[j] * sB;
    float inv = 1.f / (den + 1e-16f);
#pragma unroll
    for (int j = 0; j < 8; j++) acc[j] *= inv;

    // tiny GEMM: out[h, c8*4..+3] = sum_k agg[h][k] * W3[k][h*32+c8*4..]
    float4 o4 = {0.f, 0.f, 0.f, 0.f};
#pragma unroll
    for (int r = 0; r < 8; r++) {
#pragma unroll
        for (int j = 0; j < 8; j++) {
            float a = __shfl(acc[j], h * 8 + r, 64);
            int k = r * 8 + j;
            float4 w = *(const float4*)&W3[(size_t)k * 256 + h * 32 + c8 * 4];
            o4.x += a * w.x; o4.y += a * w.y; o4.z += a * w.z; o4.w += a * w.w;
        }
    }
    // head-mean across lanes c8, 8+c8, ..., 56+c8
#pragma unroll
    for (int o = 8; o < 64; o <<= 1) {
        o4.x += __shfl_xor(o4.x, o, 64);
        o4.y += __shfl_xor(o4.y, o, 64);
        o4.z += __shfl_xor(o4.z, o, 64);
        o4.w += __shfl_xor(o4.w, o, 64);
    }
    int cq = c8 * 4;
    o4.x = o4.x * 0.125f + b3[cq + 0];
    o4.y = o4.y * 0.125f + b3[cq + 1];
    o4.z = o4.z * 0.125f + b3[cq + 2];
    o4.w = o4.w * 0.125f + b3[cq + 3];
    float mx = fmaxf(fmaxf(o4.x, o4.y), fmaxf(o4.z, o4.w));
#pragma unroll
    for (int o = 1; o < 8; o <<= 1) mx = fmaxf(mx, __shfl_xor(mx, o, 64));
    float ex = __expf(o4.x - mx) + __expf(o4.y - mx) + __expf(o4.z - mx) + __expf(o4.w - mx);
#pragma unroll
    for (int o = 1; o < 8; o <<= 1) ex += __shfl_xor(ex, o, 64);
    float lse = mx + __logf(ex);
    if (lane < 8) {
        float4 r4 = {o4.x - lse, o4.y - lse, o4.z - lse, o4.w - lse};
        *(float4*)&out[(size_t)node * 32 + cq] = r4;
    }
}

// ---------------- host launch ----------------
extern "C" void kernel_launch(void* const* d_in, const int* in_sizes, int n_in,
                              void* d_out, int out_size, void* d_ws, size_t ws_size,
                              hipStream_t stream)
{
    const float* x   = (const float*)d_in[0];
    const int*   ei  = (const int*)  d_in[1];
    const float* W1  = (const float*)d_in[2];
    const float* as1 = (const float*)d_in[3];
    const float* ad1 = (const float*)d_in[4];
    const float* b1  = (const float*)d_in[5];
    const float* W2  = (const float*)d_in[6];
    const float* as2 = (const float*)d_in[7];
    const float* ad2 = (const float*)d_in[8];
    const float* b2  = (const float*)d_in[9];
    const float* W3  = (const float*)d_in[10];
    const float* as3 = (const float*)d_in[11];
    const float* ad3 = (const float*)d_in[12];
    const float* b3  = (const float*)d_in[13];
    float* out = (float*)d_out;

    const int N = in_sizes[0] / DIM_IN;
    const int E = in_sizes[1] / 2;
    const int Etot = E + N;

    float* ws = (float*)d_ws;
    size_t o = 0;
    float* hp1 = ws + o; o += (size_t)N * 64;
    float* p2  = ws + o; o += (size_t)N * 64;
    float* h1  = ws + o; o += (size_t)N * 64;
    float* h2  = ws + o; o += (size_t)N * 64;
    float* als = ws + o; o += (size_t)N * 8;
    float* ald = ws + o; o += (size_t)N * 8;
    float* wts = ws + o; o += 512;
    float* wtd = ws + o; o += 512;
    ushort* wpack = (ushort*)(ws + o); o += 32768;
    int* deg    = (int*)(ws + o); o += N;
    int* rowptr = (int*)(ws + o); o += N + 1;
    int* cursor = (int*)(ws + o); o += N;
    int* esrc   = (int*)(ws + o); o += Etot;
    if (o * 4 > ws_size) return;

    const int TB = 256;

    pack_w<<<64, TB, 0, stream>>>(W1, W2, wpack);
    gemm1_mfma<<<(N + 63) / 64, TB, 0, stream>>>(x, wpack, hp1, p2, N);

    hipMemsetAsync(deg, 0, (size_t)N * 4, stream);
    csr_hist<<<(Etot + TB - 1) / TB, TB, 0, stream>>>(ei, E, Etot, deg);
    csr_scan<<<1, 1024, 0, stream>>>(deg, rowptr, cursor, N);
    csr_fill<<<(Etot + TB - 1) / TB, TB, 0, stream>>>(ei, E, Etot, cursor, esrc);

    // ---- layer 1 ----
    attn_dots<8><<<(N * 8 + TB - 1) / TB, TB, 0, stream>>>(hp1, as1, ad1, als, ald, N * 8);
    gat_gather64<<<(N + 3) / 4, TB, 0, stream>>>(rowptr, esrc, als, ald, hp1, b1, h1, N);

    // p2 += h1 @ W2[1000:1064]
    gemm_k64_n64_acc<<<(N + 15) / 16, TB, 0, stream>>>(h1, W2 + (size_t)DIM_IN * 64, p2, N);

    // ---- layer 2 ----
    attn_dots<8><<<(N * 8 + TB - 1) / TB, TB, 0, stream>>>(p2, as2, ad2, als, ald, N * 8);
    gat_gather64<<<(N + 3) / 4, TB, 0, stream>>>(rowptr, esrc, als, ald, p2, b2, h2, N);

    // ---- layer 3 ----
    make_wtilde<<<1, 512, 0, stream>>>(W3, as3, ad3, wts, wtd);
    attn_dots_w<<<(N * 8 + TB - 1) / TB, TB, 0, stream>>>(h2, wts, wtd, als, ald, N * 8);
    gat_l3_final<<<(N + 3) / 4, TB, 0, stream>>>(rowptr, esrc, als, ald, h2, W3, b3, out, N);
}

// Round 7
// 577.782 us; speedup vs baseline: 1.5187x; 1.0550x over previous
//
#include <hip/hip_runtime.h>
#include <hip/hip_bf16.h>

// ---------------- constants (match reference) ----------------
#define DIM_IN 1000
#define HEADS 8
#define HID 8
#define DIM_OUT 32
#define NEG_SLOPE 0.2f
#define RESCALE_THR 8.f

typedef __attribute__((ext_vector_type(4))) float f32x4;
typedef __attribute__((ext_vector_type(8))) short s16x8;

__device__ __forceinline__ unsigned bf16rne(float f) {
    unsigned u = __float_as_uint(f);
    return (u + 0x7FFFu + ((u >> 16) & 1u)) >> 16;
}
__device__ __forceinline__ unsigned pack2(float lo, float hi) {
    return bf16rne(lo) | (bf16rne(hi) << 16);
}

// ---------------- W pre-pack: fragment-ordered bf16 [32 kt][8 ctg][64 lane][8] ----
__global__ __launch_bounds__(256) void pack_w(
    const float* __restrict__ W1, const float* __restrict__ W2,
    ushort* __restrict__ wpack)
{
    int t = blockIdx.x * 256 + threadIdx.x;   // 0..16383
    if (t >= 32 * 8 * 64) return;
    int lane = t & 63;
    int ctg = (t >> 6) & 7;
    int kt = t >> 9;
    int c = ctg * 16 + (lane & 15);
    int kbase = kt * 32 + (lane >> 4) * 8;
    ushort v[8] __attribute__((aligned(16)));
#pragma unroll
    for (int j = 0; j < 8; j++) {
        int k = kbase + j;
        float w = 0.f;
        if (k < DIM_IN) w = (c < 64) ? W1[(size_t)k * 64 + c] : W2[(size_t)k * 64 + (c - 64)];
        v[j] = (ushort)bf16rne(w);
    }
    *(uint4*)&wpack[(size_t)t * 8] = *(const uint4*)v;
}

// ---------------- GEMM1 (MFMA bf16): [N,128] = x[N,1000] @ [W1 | W2a] ----------------
__global__ __launch_bounds__(256) void gemm1_mfma(
    const float* __restrict__ x, const ushort* __restrict__ wpack,
    float* __restrict__ hp1, float* __restrict__ p2, int N)
{
    __shared__ __align__(16) ushort a_lds[2][64 * 32];
    const int tid = threadIdx.x;
    const int lane = tid & 63;
    const int wc = tid >> 6;
    const int rowbase = blockIdx.x * 64;

    const int srow = tid >> 2;
    const int skg = tid & 3;
    const int sgr = rowbase + srow;
    const int sidx = ((srow >> 4) * 64 + skg * 16 + (srow & 15)) * 8;

    f32x4 acc[4][2];
#pragma unroll
    for (int i = 0; i < 4; i++)
#pragma unroll
        for (int j = 0; j < 2; j++) acc[i][j] = (f32x4){0.f, 0.f, 0.f, 0.f};

    float4 s0, s1;
    auto load_stage = [&](int t) {
        int k0 = t * 32 + skg * 8;
        s0 = make_float4(0.f, 0.f, 0.f, 0.f);
        s1 = make_float4(0.f, 0.f, 0.f, 0.f);
        if (sgr < N && k0 + 8 <= DIM_IN) {
            const float* p = &x[(size_t)sgr * DIM_IN + k0];
            s0 = *(const float4*)p;
            s1 = *(const float4*)(p + 4);
        }
    };
    auto store_stage = [&](int buf) {
        uint4 w;
        w.x = pack2(s0.x, s0.y);
        w.y = pack2(s0.z, s0.w);
        w.z = pack2(s1.x, s1.y);
        w.w = pack2(s1.z, s1.w);
        *(uint4*)&a_lds[buf][sidx] = w;
    };

    load_stage(0);
    store_stage(0);
    __syncthreads();

    const s16x8* wp = (const s16x8*)wpack;
    for (int t = 0; t < 32; t++) {
        int cur = t & 1;
        if (t + 1 < 32) load_stage(t + 1);
        s16x8 bf0 = wp[(size_t)(t * 8 + wc * 2 + 0) * 64 + lane];
        s16x8 bf1 = wp[(size_t)(t * 8 + wc * 2 + 1) * 64 + lane];
        s16x8 af0 = *(const s16x8*)&a_lds[cur][(0 * 64 + lane) * 8];
        s16x8 af1 = *(const s16x8*)&a_lds[cur][(1 * 64 + lane) * 8];
        s16x8 af2 = *(const s16x8*)&a_lds[cur][(2 * 64 + lane) * 8];
        s16x8 af3 = *(const s16x8*)&a_lds[cur][(3 * 64 + lane) * 8];
        acc[0][0] = __builtin_amdgcn_mfma_f32_16x16x32_bf16(af0, bf0, acc[0][0], 0, 0, 0);
        acc[0][1] = __builtin_amdgcn_mfma_f32_16x16x32_bf16(af0, bf1, acc[0][1], 0, 0, 0);
        acc[1][0] = __builtin_amdgcn_mfma_f32_16x16x32_bf16(af1, bf0, acc[1][0], 0, 0, 0);
        acc[1][1] = __builtin_amdgcn_mfma_f32_16x16x32_bf16(af1, bf1, acc[1][1], 0, 0, 0);
        acc[2][0] = __builtin_amdgcn_mfma_f32_16x16x32_bf16(af2, bf0, acc[2][0], 0, 0, 0);
        acc[2][1] = __builtin_amdgcn_mfma_f32_16x16x32_bf16(af2, bf1, acc[2][1], 0, 0, 0);
        acc[3][0] = __builtin_amdgcn_mfma_f32_16x16x32_bf16(af3, bf0, acc[3][0], 0, 0, 0);
        acc[3][1] = __builtin_amdgcn_mfma_f32_16x16x32_bf16(af3, bf1, acc[3][1], 0, 0, 0);
        if (t + 1 < 32) store_stage(cur ^ 1);
        __syncthreads();
    }

    const int colbase = wc * 32;
#pragma unroll
    for (int rt = 0; rt < 4; rt++) {
        int gr = rowbase + rt * 16 + ((lane >> 4) * 4);
#pragma unroll
        for (int ctl = 0; ctl < 2; ctl++) {
            int c = colbase + ctl * 16 + (lane & 15);
            float* dst = (c < 64) ? hp1 : p2;
            int cc = (c < 64) ? c : c - 64;
#pragma unroll
            for (int reg = 0; reg < 4; reg++) {
                int r = gr + reg;
                if (r < N) dst[(size_t)r * 64 + cc] = acc[rt][ctl][reg];
            }
        }
    }
}

// ---------------- small GEMM, K=64, NC=64, out += A@W ----------------
__global__ __launch_bounds__(256) void gemm_k64_n64_acc(
    const float* __restrict__ A, const float* __restrict__ W,
    float* __restrict__ out, int N)
{
    __shared__ float as_[16][65];
    const int tid = threadIdx.x;
    const int rb = blockIdx.x * 16;
#pragma unroll
    for (int i = 0; i < 4; i++) {
        int idx = tid + i * 256;
        int r = idx >> 6, c = idx & 63;
        int gr = rb + r;
        as_[r][c] = (gr < N) ? A[(size_t)gr * 64 + c] : 0.f;
    }
    __syncthreads();
    const int row = tid >> 4;
    const int col = (tid & 15) * 4;
    float4 acc = {0, 0, 0, 0};
#pragma unroll 8
    for (int k = 0; k < 64; k++) {
        float a = as_[row][k];
        float4 w = *(const float4*)&W[k * 64 + col];
        acc.x += a * w.x; acc.y += a * w.y; acc.z += a * w.z; acc.w += a * w.w;
    }
    int gr = rb + row;
    if (gr < N) {
        float* o = &out[(size_t)gr * 64 + col];
        o[0] += acc.x; o[1] += acc.y; o[2] += acc.z; o[3] += acc.w;
    }
}

// ---------------- attention dots (per-head h layout [N,H,C], f32) ----------------
template <int C>
__global__ __launch_bounds__(256) void attn_dots(
    const float* __restrict__ h, const float* __restrict__ a_s,
    const float* __restrict__ a_d, float* __restrict__ als,
    float* __restrict__ ald, int NH)
{
    int i = blockIdx.x * blockDim.x + threadIdx.x;
    if (i >= NH) return;
    int head = i & 7;
    const float* hp = h + (size_t)i * C;
    float s = 0.f, d = 0.f;
#pragma unroll
    for (int c = 0; c < C; c++) {
        float v = hp[c];
        s += v * a_s[head * C + c];
        d += v * a_d[head * C + c];
    }
    als[i] = s; ald[i] = d;
}

// ---------------- layer-3 attention dots from bf16 h2 via wtilde ----------------
__global__ __launch_bounds__(512) void make_wtilde(
    const float* __restrict__ W3, const float* __restrict__ as3,
    const float* __restrict__ ad3, float* __restrict__ wts,
    float* __restrict__ wtd)
{
    int t = threadIdx.x;
    int h = t >> 6, k = t & 63;
    float s = 0.f, d = 0.f;
#pragma unroll
    for (int c = 0; c < 32; c++) {
        float w = W3[(size_t)k * 256 + h * 32 + c];
        s += w * as3[h * 32 + c];
        d += w * ad3[h * 32 + c];
    }
    wts[h * 64 + k] = s;
    wtd[h * 64 + k] = d;
}

__global__ __launch_bounds__(256) void attn_dots_w(
    const ushort* __restrict__ h2b, const float* __restrict__ wts,
    const float* __restrict__ wtd, float* __restrict__ als,
    float* __restrict__ ald, int NH)
{
    int i = blockIdx.x * blockDim.x + threadIdx.x;
    if (i >= NH) return;
    int head = i & 7, node = i >> 3;
    const uint4* hp = (const uint4*)(h2b + (size_t)node * 64);
    const float* wsp = wts + head * 64;
    const float* wdp = wtd + head * 64;
    float s = 0.f, d = 0.f;
#pragma unroll
    for (int cq = 0; cq < 8; cq++) {
        uint4 q = hp[cq];
        float f0 = __uint_as_float(q.x << 16), f1 = __uint_as_float(q.x & 0xFFFF0000u);
        float f2 = __uint_as_float(q.y << 16), f3 = __uint_as_float(q.y & 0xFFFF0000u);
        float f4 = __uint_as_float(q.z << 16), f5 = __uint_as_float(q.z & 0xFFFF0000u);
        float f6 = __uint_as_float(q.w << 16), f7 = __uint_as_float(q.w & 0xFFFF0000u);
        int c = cq * 8;
        s += f0 * wsp[c] + f1 * wsp[c + 1] + f2 * wsp[c + 2] + f3 * wsp[c + 3]
           + f4 * wsp[c + 4] + f5 * wsp[c + 5] + f6 * wsp[c + 6] + f7 * wsp[c + 7];
        d += f0 * wdp[c] + f1 * wdp[c + 1] + f2 * wdp[c + 2] + f3 * wdp[c + 3]
           + f4 * wdp[c + 4] + f5 * wdp[c + 5] + f6 * wdp[c + 6] + f7 * wdp[c + 7];
    }
    als[i] = s; ald[i] = d;
}

// ---------------- CSR build ----------------
__global__ __launch_bounds__(256) void csr_hist(
    const int* __restrict__ ei, int E, int Etot, int* __restrict__ deg)
{
    int e = blockIdx.x * blockDim.x + threadIdx.x;
    if (e >= Etot) return;
    int d = (e < E) ? ei[E + e] : e - E;
    atomicAdd(&deg[d], 1);
}

__global__ __launch_bounds__(1024) void csr_scan(
    const int* __restrict__ deg, int* __restrict__ rowptr,
    int* __restrict__ cursor, int N)
{
    __shared__ int partial[1024];
    const int t = threadIdx.x;
    const int chunk = (N + 1023) >> 10;
    const int lo = t * chunk;
    const int hi = min(N, lo + chunk);
    int s = 0;
    for (int i = lo; i < hi; i++) s += deg[i];
    partial[t] = s;
    __syncthreads();
    for (int off = 1; off < 1024; off <<= 1) {
        int v = (t >= off) ? partial[t - off] : 0;
        __syncthreads();
        partial[t] += v;
        __syncthreads();
    }
    int run = (t == 0) ? 0 : partial[t - 1];
    for (int i = lo; i < hi; i++) {
        rowptr[i] = run;
        cursor[i] = run;
        run += deg[i];
    }
    if (t == 1023) rowptr[N] = partial[1023];
}

__global__ __launch_bounds__(256) void csr_fill(
    const int* __restrict__ ei, int E, int Etot,
    int* __restrict__ cursor, int* __restrict__ esrc)
{
    int e = blockIdx.x * blockDim.x + threadIdx.x;
    if (e >= Etot) return;
    int s, d;
    if (e < E) { s = ei[e]; d = ei[E + e]; } else { s = d = e - E; }
    int pos = atomicAdd(&cursor[d], 1);
    esrc[pos] = s;
}

// ---------------- fused gather layer (C=64): pipelined (idx 2 batches ahead,
// data 1 batch ahead), 2-stream defer-max online softmax + bias + ELU ----------------
template <bool OUT_BF16>
__global__ __launch_bounds__(256) void gat_gather64(
    const int* __restrict__ rowptr, const int* __restrict__ esrc,
    const float* __restrict__ als, const float* __restrict__ ald,
    const float* __restrict__ h, const float* __restrict__ bias,
    float* __restrict__ outf, ushort* __restrict__ outb, int N)
{
    int node = blockIdx.x * 4 + (threadIdx.x >> 6);
    if (node >= N) return;
    int lane = threadIdx.x & 63;
    int head = lane >> 3;
    int start = rowptr[node];
    int cnt = rowptr[node + 1] - start;
    float aldv = ald[(size_t)node * 8 + head];

    float mA = -1e30f, dA = 0.f, aA = 0.f;
    float mB = -1e30f, dB = 0.f, aB = 0.f;

    auto gi = [&](int k) { return esrc[start + (k < cnt ? k : cnt - 1)]; };
    auto idx4 = [&](int k) {
        int4 r; r.x = gi(k); r.y = gi(k + 1); r.z = gi(k + 2); r.w = gi(k + 3);
        return r;
    };
    auto issue = [&](int4 s, float4& ee, float4& hh) {
        ee.x = als[(size_t)s.x * 8 + head];
        ee.y = als[(size_t)s.y * 8 + head];
        ee.z = als[(size_t)s.z * 8 + head];
        ee.w = als[(size_t)s.w * 8 + head];
        hh.x = h[(size_t)s.x * 64 + lane];
        hh.y = h[(size_t)s.y * 64 + lane];
        hh.z = h[(size_t)s.z * 64 + lane];
        hh.w = h[(size_t)s.w * 64 + lane];
    };
    auto upedge = [&](float e, float hv, float& m, float& d, float& a) {
        if (__any(e - m > RESCALE_THR)) {
            float nm = fmaxf(m, e), sc = __expf(m - nm);
            a *= sc; d *= sc; m = nm;
        }
        float ee = __expf(e - m);
        d += ee; a = fmaf(ee, hv, a);
    };
    auto lrelu = [&](float e, int k) {
        e += aldv;
        e = (e > 0.f) ? e : NEG_SLOPE * e;
        return (k < cnt) ? e : -1e30f;
    };
    auto upd = [&](int base, float4 ee, float4 hh) {
        if (base >= cnt) return;
        upedge(lrelu(ee.x, base + 0), hh.x, mA, dA, aA);
        upedge(lrelu(ee.y, base + 1), hh.y, mA, dA, aA);
        upedge(lrelu(ee.z, base + 2), hh.z, mB, dB, aB);
        upedge(lrelu(ee.w, base + 3), hh.w, mB, dB, aB);
    };

    int4 i0 = idx4(0), i1 = idx4(4);
    float4 e0, h0, e1, h1;
    issue(i0, e0, h0);
    int nb = (cnt + 3) >> 2;
    for (int b = 0; b < nb; b += 2) {
        i0 = idx4((b + 2) * 4);
        issue(i1, e1, h1);
        upd(b * 4, e0, h0);
        i1 = idx4((b + 3) * 4);
        issue(i0, e0, h0);
        upd((b + 1) * 4, e1, h1);
    }
    float m = fmaxf(mA, mB);
    float sA = __expf(mA - m), sB = __expf(mB - m);
    float den = dA * sA + dB * sB;
    float acc = aA * sA + aB * sB;
    float v = acc / (den + 1e-16f) + bias[lane];
    v = (v > 0.f) ? v : (__expf(v) - 1.f);
    if (OUT_BF16) outb[(size_t)node * 64 + lane] = (ushort)bf16rne(v);
    else outf[(size_t)node * 64 + lane] = v;
}

// ---------------- layer 3 fully fused: pipelined bf16-h2 gather + defer-max,
// tiny per-head GEMM with W3, head-mean, bias, log_softmax ----------------
__global__ __launch_bounds__(256) void gat_l3_final(
    const int* __restrict__ rowptr, const int* __restrict__ esrc,
    const float* __restrict__ als, const float* __restrict__ ald,
    const ushort* __restrict__ h2b, const float* __restrict__ W3,
    const float* __restrict__ b3, float* __restrict__ out, int N)
{
    int node = blockIdx.x * 4 + (threadIdx.x >> 6);
    if (node >= N) return;
    int lane = threadIdx.x & 63;
    int h = lane >> 3, c8 = lane & 7;
    int start = rowptr[node];
    int cnt = rowptr[node + 1] - start;
    float aldv = ald[(size_t)node * 8 + h];

    float mA = -1e30f, dA = 0.f, mB = -1e30f, dB = 0.f;
    float accA[8] = {}, accB[8] = {};

    auto gi = [&](int k) { return esrc[start + (k < cnt ? k : cnt - 1)]; };
    auto idx4 = [&](int k) {
        int4 r; r.x = gi(k); r.y = gi(k + 1); r.z = gi(k + 2); r.w = gi(k + 3);
        return r;
    };
    auto issue = [&](int4 s, float4& ee, uint4& q0, uint4& q1, uint4& q2, uint4& q3) {
        ee.x = als[(size_t)s.x * 8 + h];
        ee.y = als[(size_t)s.y * 8 + h];
        ee.z = als[(size_t)s.z * 8 + h];
        ee.w = als[(size_t)s.w * 8 + h];
        q0 = *(const uint4*)&h2b[(size_t)s.x * 64 + c8 * 8];
        q1 = *(const uint4*)&h2b[(size_t)s.y * 64 + c8 * 8];
        q2 = *(const uint4*)&h2b[(size_t)s.z * 64 + c8 * 8];
        q3 = *(const uint4*)&h2b[(size_t)s.w * 64 + c8 * 8];
    };
    auto upedge = [&](float e, uint4 q, float& m, float& d, float (&a)[8]) {
        if (__any(e - m > RESCALE_THR)) {
            float nm = fmaxf(m, e), sc = __expf(m - nm);
            d *= sc;
#pragma unroll
            for (int j = 0; j < 8; j++) a[j] *= sc;
            m = nm;
        }
        float ee = __expf(e - m);
        d += ee;
        a[0] = fmaf(ee, __uint_as_float(q.x << 16), a[0]);
        a[1] = fmaf(ee, __uint_as_float(q.x & 0xFFFF0000u), a[1]);
        a[2] = fmaf(ee, __uint_as_float(q.y << 16), a[2]);
        a[3] = fmaf(ee, __uint_as_float(q.y & 0xFFFF0000u), a[3]);
        a[4] = fmaf(ee, __uint_as_float(q.z << 16), a[4]);
        a[5] = fmaf(ee, __uint_as_float(q.z & 0xFFFF0000u), a[5]);
        a[6] = fmaf(ee, __uint_as_float(q.w << 16), a[6]);
        a[7] = fmaf(ee, __uint_as_float(q.w & 0xFFFF0000u), a[7]);
    };
    auto lrelu = [&](float e, int k) {
        e += aldv;
        e = (e > 0.f) ? e : NEG_SLOPE * e;
        return (k < cnt) ? e : -1e30f;
    };
    auto upd = [&](int base, float4 ee, uint4 q0, uint4 q1, uint4 q2, uint4 q3) {
        if (base >= cnt) return;
        upedge(lrelu(ee.x, base + 0), q0, mA, dA, accA);
        upedge(lrelu(ee.y, base + 1), q1, mA, dA, accA);
        upedge(lrelu(ee.z, base + 2), q2, mB, dB, accB);
        upedge(lrelu(ee.w, base + 3), q3, mB, dB, accB);
    };

    int4 i0 = idx4(0), i1 = idx4(4);
    float4 eC, eD;
    uint4 q0C, q1C, q2C, q3C, q0D, q1D, q2D, q3D;
    issue(i0, eC, q0C, q1C, q2C, q3C);
    int nb = (cnt + 3) >> 2;
    for (int b = 0; b < nb; b += 2) {
        i0 = idx4((b + 2) * 4);
        issue(i1, eD, q0D, q1D, q2D, q3D);
        upd(b * 4, eC, q0C, q1C, q2C, q3C);
        i1 = idx4((b + 3) * 4);
        issue(i0, eC, q0C, q1C, q2C, q3C);
        upd((b + 1) * 4, eD, q0D, q1D, q2D, q3D);
    }

    float mm = fmaxf(mA, mB);
    float sA = __expf(mA - mm), sB = __expf(mB - mm);
    float den = dA * sA + dB * sB;
    float inv = 1.f / (den + 1e-16f);
    float acc[8];
#pragma unroll
    for (int j = 0; j < 8; j++) acc[j] = (accA[j] * sA + accB[j] * sB) * inv;

    // tiny GEMM: out[h, c8*4..+3] = sum_k agg[h][k] * W3[k][h*32+c8*4..]
    float4 o4 = {0.f, 0.f, 0.f, 0.f};
#pragma unroll
    for (int r = 0; r < 8; r++) {
#pragma unroll
        for (int j = 0; j < 8; j++) {
            float a = __shfl(acc[j], h * 8 + r, 64);
            int k = r * 8 + j;
            float4 w = *(const float4*)&W3[(size_t)k * 256 + h * 32 + c8 * 4];
            o4.x += a * w.x; o4.y += a * w.y; o4.z += a * w.z; o4.w += a * w.w;
        }
    }
    // head-mean across lanes c8, 8+c8, ..., 56+c8
#pragma unroll
    for (int o = 8; o < 64; o <<= 1) {
        o4.x += __shfl_xor(o4.x, o, 64);
        o4.y += __shfl_xor(o4.y, o, 64);
        o4.z += __shfl_xor(o4.z, o, 64);
        o4.w += __shfl_xor(o4.w, o, 64);
    }
    int cq = c8 * 4;
    o4.x = o4.x * 0.125f + b3[cq + 0];
    o4.y = o4.y * 0.125f + b3[cq + 1];
    o4.z = o4.z * 0.125f + b3[cq + 2];
    o4.w = o4.w * 0.125f + b3[cq + 3];
    float mx = fmaxf(fmaxf(o4.x, o4.y), fmaxf(o4.z, o4.w));
#pragma unroll
    for (int o = 1; o < 8; o <<= 1) mx = fmaxf(mx, __shfl_xor(mx, o, 64));
    float ex = __expf(o4.x - mx) + __expf(o4.y - mx) + __expf(o4.z - mx) + __expf(o4.w - mx);
#pragma unroll
    for (int o = 1; o < 8; o <<= 1) ex += __shfl_xor(ex, o, 64);
    float lse = mx + __logf(ex);
    if (lane < 8) {
        float4 r4 = {o4.x - lse, o4.y - lse, o4.z - lse, o4.w - lse};
        *(float4*)&out[(size_t)node * 32 + cq] = r4;
    }
}

// ---------------- host launch ----------------
extern "C" void kernel_launch(void* const* d_in, const int* in_sizes, int n_in,
                              void* d_out, int out_size, void* d_ws, size_t ws_size,
                              hipStream_t stream)
{
    const float* x   = (const float*)d_in[0];
    const int*   ei  = (const int*)  d_in[1];
    const float* W1  = (const float*)d_in[2];
    const float* as1 = (const float*)d_in[3];
    const float* ad1 = (const float*)d_in[4];
    const float* b1  = (const float*)d_in[5];
    const float* W2  = (const float*)d_in[6];
    const float* as2 = (const float*)d_in[7];
    const float* ad2 = (const float*)d_in[8];
    const float* b2  = (const float*)d_in[9];
    const float* W3  = (const float*)d_in[10];
    const float* as3 = (const float*)d_in[11];
    const float* ad3 = (const float*)d_in[12];
    const float* b3  = (const float*)d_in[13];
    float* out = (float*)d_out;

    const int N = in_sizes[0] / DIM_IN;
    const int E = in_sizes[1] / 2;
    const int Etot = E + N;

    float* ws = (float*)d_ws;
    size_t o = 0;
    float* hp1 = ws + o; o += (size_t)N * 64;
    float* p2  = ws + o; o += (size_t)N * 64;
    float* h1  = ws + o; o += (size_t)N * 64;
    ushort* h2b = (ushort*)(ws + o); o += (size_t)N * 32;   // bf16 h2
    float* als = ws + o; o += (size_t)N * 8;
    float* ald = ws + o; o += (size_t)N * 8;
    float* wts = ws + o; o += 512;
    float* wtd = ws + o; o += 512;
    ushort* wpack = (ushort*)(ws + o); o += 32768;
    int* deg    = (int*)(ws + o); o += N;
    int* rowptr = (int*)(ws + o); o += N + 1;
    int* cursor = (int*)(ws + o); o += N;
    int* esrc   = (int*)(ws + o); o += Etot;
    if (o * 4 > ws_size) return;

    const int TB = 256;

    pack_w<<<64, TB, 0, stream>>>(W1, W2, wpack);
    gemm1_mfma<<<(N + 63) / 64, TB, 0, stream>>>(x, wpack, hp1, p2, N);

    hipMemsetAsync(deg, 0, (size_t)N * 4, stream);
    csr_hist<<<(Etot + TB - 1) / TB, TB, 0, stream>>>(ei, E, Etot, deg);
    csr_scan<<<1, 1024, 0, stream>>>(deg, rowptr, cursor, N);
    csr_fill<<<(Etot + TB - 1) / TB, TB, 0, stream>>>(ei, E, Etot, cursor, esrc);

    // ---- layer 1 ----
    attn_dots<8><<<(N * 8 + TB - 1) / TB, TB, 0, stream>>>(hp1, as1, ad1, als, ald, N * 8);
    gat_gather64<false><<<(N + 3) / 4, TB, 0, stream>>>(rowptr, esrc, als, ald, hp1, b1, h1, nullptr, N);

    // p2 += h1 @ W2[1000:1064]
    gemm_k64_n64_acc<<<(N + 15) / 16, TB, 0, stream>>>(h1, W2 + (size_t)DIM_IN * 64, p2, N);

    // ---- layer 2 (bf16 output) ----
    attn_dots<8><<<(N * 8 + TB - 1) / TB, TB, 0, stream>>>(p2, as2, ad2, als, ald, N * 8);
    gat_gather64<true><<<(N + 3) / 4, TB, 0, stream>>>(rowptr, esrc, als, ald, p2, b2, nullptr, h2b, N);

    // ---- layer 3 ----
    make_wtilde<<<1, 512, 0, stream>>>(W3, as3, ad3, wts, wtd);
    attn_dots_w<<<(N * 8 + TB - 1) / TB, TB, 0, stream>>>(h2b, wts, wtd, als, ald, N * 8);
    gat_l3_final<<<(N + 3) / 4, TB, 0, stream>>>(rowptr, esrc, als, ald, h2b, W3, b3, out, N);
}